// Round 3
// baseline (798.322 us; speedup 1.0000x reference)
//
#include <hip/hip_runtime.h>

#define B_ 8
#define N_ 2048
#define K_ 30
#define H_ 128
#define LDA 136
#define EPS_ 1e-5f

typedef __attribute__((ext_vector_type(8))) short short8;
typedef __attribute__((ext_vector_type(4))) float f32x4;

__device__ inline unsigned short f2bf(float f) {
  union { float f; unsigned u; } v; v.f = f;
  unsigned r = v.u + 0x7fffu + ((v.u >> 16) & 1u);
  return (unsigned short)(r >> 16);
}

__device__ inline float bf2f(unsigned short h) {
  union { unsigned u; float f; } v; v.u = ((unsigned)h) << 16; return v.f;
}

__device__ inline float gelu_f(float x) {
  return 0.5f * x * (1.0f + erff(x * 0.70710678118654752f));
}

__device__ inline short8 pack8(float4 a, float4 b) {
  short8 o;
  o[0] = (short)f2bf(a.x); o[1] = (short)f2bf(a.y); o[2] = (short)f2bf(a.z); o[3] = (short)f2bf(a.w);
  o[4] = (short)f2bf(b.x); o[5] = (short)f2bf(b.y); o[6] = (short)f2bf(b.z); o[7] = (short)f2bf(b.w);
  return o;
}

#define ZERO_ACC(A) \
  _Pragma("unroll") for (int m_ = 0; m_ < 4; ++m_) \
  _Pragma("unroll") for (int n_ = 0; n_ < 4; ++n_) A[m_][n_] = (f32x4){0.f, 0.f, 0.f, 0.f};

// ---- GEMM chunk with A-fragments loaded DIRECTLY from global bf16 rows ----
// rp(m, row) -> global bf16 row base for that A row. W row-major [out][LDW].
template<int LDW, typename RP>
__device__ inline void gemm_direct_bf16(RP rp, const unsigned short* __restrict__ W,
                                        int lane, int wr, int wcid, f32x4 (&acc)[4][4]) {
  const int rl = lane & 15;
  const int klo = (lane >> 4) << 3;
  short8 a[4][4];
#pragma unroll
  for (int ks = 0; ks < 4; ++ks)
#pragma unroll
    for (int m = 0; m < 4; ++m)
      a[ks][m] = *(const short8*)(rp(m, wr * 64 + m * 16 + rl) + ks * 32 + klo);
#pragma unroll
  for (int ks = 0; ks < 4; ++ks)
#pragma unroll
    for (int n = 0; n < 4; ++n) {
      const short8 b8 = *(const short8*)(W + (size_t)(wcid * 64 + n * 16 + rl) * LDW + ks * 32 + klo);
#pragma unroll
      for (int m = 0; m < 4; ++m)
        acc[m][n] = __builtin_amdgcn_mfma_f32_16x16x32_bf16(a[ks][m], b8, acc[m][n], 0, 0, 0);
    }
}

// same but A rows are fp32 in global (converted inline)
template<int LDW, typename RP>
__device__ inline void gemm_direct_f32(RP rp, const unsigned short* __restrict__ W,
                                       int lane, int wr, int wcid, f32x4 (&acc)[4][4]) {
  const int rl = lane & 15;
  const int klo = (lane >> 4) << 3;
#pragma unroll
  for (int ks = 0; ks < 4; ++ks) {
    short8 a[4];
#pragma unroll
    for (int m = 0; m < 4; ++m) {
      const float* s = rp(m, wr * 64 + m * 16 + rl) + ks * 32 + klo;
      a[m] = pack8(*(const float4*)s, *(const float4*)(s + 4));
    }
#pragma unroll
    for (int n = 0; n < 4; ++n) {
      const short8 b8 = *(const short8*)(W + (size_t)(wcid * 64 + n * 16 + rl) * LDW + ks * 32 + klo);
#pragma unroll
      for (int m = 0; m < 4; ++m)
        acc[m][n] = __builtin_amdgcn_mfma_f32_16x16x32_bf16(a[m], b8, acc[m][n], 0, 0, 0);
    }
  }
}

// ---- wave-level GEMM with A from LDS (for post-transpose stages) ----
template<int LDW>
__device__ inline void wave_gemm(const unsigned short* __restrict__ sSrc,
                                 const unsigned short* __restrict__ W,
                                 int lane, int wr, int wcid, f32x4 (&acc)[4][4]) {
#pragma unroll
  for (int ks = 0; ks < 4; ++ks) {
    const int kk = ks * 32 + ((lane >> 4) << 3);
    short8 a[4];
#pragma unroll
    for (int m = 0; m < 4; ++m)
      a[m] = *(const short8*)(sSrc + (wr * 64 + m * 16 + (lane & 15)) * LDA + kk);
#pragma unroll
    for (int n = 0; n < 4; ++n) {
      const short8 bfr = *(const short8*)(W + (size_t)(wcid * 64 + n * 16 + (lane & 15)) * LDW + kk);
#pragma unroll
      for (int m = 0; m < 4; ++m)
        acc[m][n] = __builtin_amdgcn_mfma_f32_16x16x32_bf16(a[m], bfr, acc[m][n], 0, 0, 0);
    }
  }
}

__device__ inline void bias_gelu_store(const f32x4 (&acc)[4][4], const float* __restrict__ bias,
                                       unsigned short* __restrict__ dst, int lane, int wr, int wcid) {
#pragma unroll
  for (int n = 0; n < 4; ++n) {
    const int col = wcid * 64 + n * 16 + (lane & 15);
    const float bb = bias[col];
#pragma unroll
    for (int m = 0; m < 4; ++m) {
#pragma unroll
      for (int i = 0; i < 4; ++i) {
        const int row = wr * 64 + m * 16 + ((lane >> 4) << 2) + i;
        dst[row * LDA + col] = f2bf(gelu_f(acc[m][n][i] + bb));
      }
    }
  }
}

// ---- prep: weights fp32 -> bf16 ----
__global__ __launch_bounds__(256) void prep(const float* __restrict__ w1, const float* __restrict__ w2,
                                            const float* __restrict__ w3, const float* __restrict__ w11,
                                            const float* __restrict__ w12, const float* __restrict__ w13,
                                            const float* __restrict__ din, const float* __restrict__ dout,
                                            unsigned short* __restrict__ dst) {
  const int i = blockIdx.x * 256 + threadIdx.x;  // grid covers exactly 294912
  const float* s; int off;
  if (i < 49152)       { s = w1;  off = 0; }
  else if (i < 65536)  { s = w2;  off = 49152; }
  else if (i < 81920)  { s = w3;  off = 65536; }
  else if (i < 131072) { s = w11; off = 81920; }
  else if (i < 147456) { s = w12; off = 131072; }
  else if (i < 163840) { s = w13; off = 147456; }
  else if (i < 229376) { s = din; off = 163840; }
  else                 { s = dout; off = 229376; }
  dst[i] = f2bf(s[i - off]);
}

// ---- cvt8: fp32 -> bf16, 8 elems/thread ----
__global__ __launch_bounds__(256) void cvt8(const float* __restrict__ src,
                                            unsigned short* __restrict__ dst, int n8) {
  const int i = blockIdx.x * 256 + threadIdx.x;
  if (i >= n8) return;
  const float4 a = ((const float4*)src)[i * 2];
  const float4 b = ((const float4*)src)[i * 2 + 1];
  ((short8*)dst)[i] = pack8(a, b);
}

// ---- k1: node message MLP + masked k-sum + LN1 -> hV1b (bf16) ----
__global__ __launch_bounds__(256, 3) void k1(
    const float* __restrict__ hV, const unsigned short* __restrict__ hVb,
    const float* __restrict__ hE,
    const int* __restrict__ Eidx, const float* __restrict__ mattend,
    const unsigned short* __restrict__ wc,
    const float* __restrict__ W1b, const float* __restrict__ W2b,
    const float* __restrict__ W3b, const float* __restrict__ n1g,
    const float* __restrict__ n1b, unsigned short* __restrict__ hV1b) {
  __shared__ __align__(16) unsigned short sA[128 * LDA];
  __shared__ float sRed[4][128];

  const int tid = threadIdx.x;
  const int lane = tid & 63;
  const int w = tid >> 6;
  const int wr = w >> 1, wcid = w & 1;
  const int bid = (blockIdx.x & 7) * 512 + (blockIdx.x >> 3);  // XCD: one batch per XCD
  const int v0 = bid << 2;
  const int b = v0 >> 11;
  const int n0 = v0 & (N_ - 1);
  const int bBase = b * N_;
  const int rl = lane & 15;

  const unsigned short* W1c = wc;          // [128][384]
  const unsigned short* W2c = wc + 49152;  // [128][128]
  const unsigned short* W3c = wc + 65536;  // [128][128]

  // prefetch gather indices for this lane's A rows
  int jrow[4];
#pragma unroll
  for (int m = 0; m < 4; ++m) {
    const int row = wr * 64 + m * 16 + rl;
    const int g = row >> 5;
    int kk = row & 31; if (kk >= K_) kk = K_ - 1;
    jrow[m] = Eidx[(bBase + n0 + g) * K_ + kk];
  }

  f32x4 acc[4][4];
  ZERO_ACC(acc)

  // chunk 0: center hV rows (broadcast within node)
  gemm_direct_bf16<384>([&](int m, int row) {
    return hVb + (((size_t)(bBase + n0 + (row >> 5))) << 7);
  }, W1c, lane, wr, wcid, acc);
  // chunk 1: gathered hV rows
  gemm_direct_bf16<384>([&](int m, int row) {
    return hVb + (((size_t)(bBase + jrow[m])) << 7);
  }, W1c + 128, lane, wr, wcid, acc);
  // chunk 2: hE rows (fp32, inline convert)
  gemm_direct_f32<384>([&](int m, int row) {
    const int g = row >> 5;
    int kk = row & 31; if (kk >= K_) kk = K_ - 1;
    return hE + (((size_t)((bBase + n0 + g) * K_ + kk)) << 7);
  }, W1c + 256, lane, wr, wcid, acc);

  bias_gelu_store(acc, W1b, sA, lane, wr, wcid);
  __syncthreads();

  f32x4 acc2[4][4];
  ZERO_ACC(acc2)
  wave_gemm<128>(sA, W2c, lane, wr, wcid, acc2);
  __syncthreads();
  bias_gelu_store(acc2, W2b, sA, lane, wr, wcid);
  __syncthreads();

  f32x4 acc3[4][4];
  ZERO_ACC(acc3)
  wave_gemm<128>(sA, W3c, lane, wr, wcid, acc3);

  // bias + mask + sum over k rows -> sRed[node][col]
#pragma unroll
  for (int mp = 0; mp < 2; ++mp) {
    const int g = wr * 2 + mp;
    float mk[2][4];
#pragma unroll
    for (int mh = 0; mh < 2; ++mh)
#pragma unroll
      for (int i = 0; i < 4; ++i) {
        const int kk = mh * 16 + ((lane >> 4) << 2) + i;
        mk[mh][i] = (kk < K_) ? mattend[(bBase + n0 + g) * K_ + kk] : 0.f;
      }
#pragma unroll
    for (int n = 0; n < 4; ++n) {
      const int col = wcid * 64 + n * 16 + rl;
      const float bb = W3b[col];
      float s = 0.f;
#pragma unroll
      for (int mh = 0; mh < 2; ++mh)
#pragma unroll
        for (int i = 0; i < 4; ++i)
          s += (acc3[mp * 2 + mh][n][i] + bb) * mk[mh][i];
      s += __shfl_xor(s, 16);
      s += __shfl_xor(s, 32);
      if (lane < 16) sRed[g][col] = s;
    }
  }
  __syncthreads();

  // residual + LN1, one wave per node -> bf16
  {
    const int g = w;
    const size_t base = ((size_t)(bBase + n0 + g)) << 7;
    const float x0 = hV[base + lane] + sRed[g][lane] * (1.0f / 30.0f);
    const float x1 = hV[base + 64 + lane] + sRed[g][64 + lane] * (1.0f / 30.0f);
    float s = x0 + x1;
#pragma unroll
    for (int o = 1; o < 64; o <<= 1) s += __shfl_xor(s, o);
    const float mean = s * (1.0f / 128.0f);
    const float d0 = x0 - mean, d1 = x1 - mean;
    float vs = d0 * d0 + d1 * d1;
#pragma unroll
    for (int o = 1; o < 64; o <<= 1) vs += __shfl_xor(vs, o);
    const float inv = rsqrtf(vs * (1.0f / 128.0f) + EPS_);
    hV1b[base + lane] = f2bf(n1g[lane] * (d0 * inv) + n1b[lane]);
    hV1b[base + 64 + lane] = f2bf(n1g[64 + lane] * (d1 * inv) + n1b[64 + lane]);
  }
}

// ---- k2: FFN + LN2 + mask_V -> outV (fp32) and hV2c (bf16); 64 rows/block ----
__global__ __launch_bounds__(256) void k2(
    const unsigned short* __restrict__ hV1b, const unsigned short* __restrict__ wc,
    const float* __restrict__ dinb, const float* __restrict__ doutb,
    const float* __restrict__ n2g, const float* __restrict__ n2b,
    const float* __restrict__ maskV, float* __restrict__ outV,
    unsigned short* __restrict__ hV2c) {
  __shared__ __align__(16) unsigned short sT[64 * LDA];
  __shared__ float sStat[64][2][4];

  const int tid = threadIdx.x;
  const int lane = tid & 63;
  const int w = tid >> 6;
  const int rowbase = blockIdx.x << 6;
  const int rl = lane & 15;
  const int klo = (lane >> 4) << 3;

  const unsigned short* dinc = wc + 163840;   // [512][128]
  const unsigned short* doutc = wc + 229376;  // [128][512]

  // hoist A (64 rows x 128 of hV1b) fragments: constant across chunks
  short8 a[4][4];
#pragma unroll
  for (int ks = 0; ks < 4; ++ks)
#pragma unroll
    for (int m = 0; m < 4; ++m)
      a[ks][m] = *(const short8*)(hV1b + (((size_t)(rowbase + m * 16 + rl)) << 7) + ks * 32 + klo);

  f32x4 acc2[4][2];
#pragma unroll
  for (int m = 0; m < 4; ++m) { acc2[m][0] = (f32x4){0,0,0,0}; acc2[m][1] = (f32x4){0,0,0,0}; }

  for (int c = 0; c < 4; ++c) {
    f32x4 acc1[4][2];
#pragma unroll
    for (int m = 0; m < 4; ++m) { acc1[m][0] = (f32x4){0,0,0,0}; acc1[m][1] = (f32x4){0,0,0,0}; }
    // GEMM1 chunk: out-cols c*128 + (w*32 + n*16 + rl)
#pragma unroll
    for (int ks = 0; ks < 4; ++ks)
#pragma unroll
      for (int n = 0; n < 2; ++n) {
        const short8 b8 = *(const short8*)(dinc + (size_t)(c * 128 + w * 32 + n * 16 + rl) * 128 + ks * 32 + klo);
#pragma unroll
        for (int m = 0; m < 4; ++m)
          acc1[m][n] = __builtin_amdgcn_mfma_f32_16x16x32_bf16(a[ks][m], b8, acc1[m][n], 0, 0, 0);
      }
    __syncthreads();  // previous chunk's GEMM2 reads of sT done
#pragma unroll
    for (int n = 0; n < 2; ++n) {
      const int col = w * 32 + n * 16 + rl;
      const float bb = dinb[c * 128 + col];
#pragma unroll
      for (int m = 0; m < 4; ++m)
#pragma unroll
        for (int i = 0; i < 4; ++i)
          sT[(m * 16 + ((lane >> 4) << 2) + i) * LDA + col] = f2bf(gelu_f(acc1[m][n][i] + bb));
    }
    __syncthreads();
    // GEMM2 chunk: A = sT [64 x 128], B rows = dout[ofeat][c*128..]
#pragma unroll
    for (int ks = 0; ks < 4; ++ks) {
      short8 a2[4];
#pragma unroll
      for (int m = 0; m < 4; ++m)
        a2[m] = *(const short8*)(sT + (m * 16 + rl) * LDA + ks * 32 + klo);
#pragma unroll
      for (int n = 0; n < 2; ++n) {
        const short8 b8 = *(const short8*)(doutc + (size_t)(w * 32 + n * 16 + rl) * 512 + c * 128 + ks * 32 + klo);
#pragma unroll
        for (int m = 0; m < 4; ++m)
          acc2[m][n] = __builtin_amdgcn_mfma_f32_16x16x32_bf16(a2[m], b8, acc2[m][n], 0, 0, 0);
      }
    }
  }

  // epilogue: residual + LN2 + mask
  float gc[2], bc[2], wb[2];
#pragma unroll
  for (int n = 0; n < 2; ++n) {
    const int col = w * 32 + n * 16 + rl;
    gc[n] = n2g[col]; bc[n] = n2b[col]; wb[n] = doutb[col];
  }
#pragma unroll
  for (int m = 0; m < 4; ++m) {
#pragma unroll
    for (int i = 0; i < 4; ++i) {
      const int row = m * 16 + ((lane >> 4) << 2) + i;
      const unsigned short* rr = hV1b + (((size_t)(rowbase + row)) << 7) + w * 32 + rl;
      float s = 0.f, ss = 0.f;
#pragma unroll
      for (int n = 0; n < 2; ++n) {
        float x = acc2[m][n][i] + wb[n] + bf2f(rr[n * 16]);
        acc2[m][n][i] = x;
        s += x; ss += x * x;
      }
#pragma unroll
      for (int o = 1; o <= 8; o <<= 1) { s += __shfl_xor(s, o); ss += __shfl_xor(ss, o); }
      if (rl == 0) { sStat[row][0][w] = s; sStat[row][1][w] = ss; }
    }
  }
  __syncthreads();
#pragma unroll
  for (int m = 0; m < 4; ++m) {
#pragma unroll
    for (int i = 0; i < 4; ++i) {
      const int row = m * 16 + ((lane >> 4) << 2) + i;
      const int grow = rowbase + row;
      const float sum = sStat[row][0][0] + sStat[row][0][1] + sStat[row][0][2] + sStat[row][0][3];
      const float ssq = sStat[row][1][0] + sStat[row][1][1] + sStat[row][1][2] + sStat[row][1][3];
      const float mean = sum * (1.0f / 128.0f);
      const float inv = rsqrtf(ssq * (1.0f / 128.0f) - mean * mean + EPS_);
      const float mv = maskV[grow];
      float* dst = outV + (((size_t)grow) << 7) + w * 32 + rl;
      unsigned short* dstc = hV2c + (((size_t)grow) << 7) + w * 32 + rl;
#pragma unroll
      for (int n = 0; n < 2; ++n) {
        const float y = (gc[n] * (acc2[m][n][i] - mean) * inv + bc[n]) * mv;
        dst[n * 16] = y;
        dstc[n * 16] = f2bf(y);
      }
    }
  }
}

// ---- k3: edge message MLP + residual + LN3 -> outE ----
__global__ __launch_bounds__(256, 3) void k3(
    const unsigned short* __restrict__ hV2c, const float* __restrict__ hE,
    const int* __restrict__ Eidx, const unsigned short* __restrict__ wc,
    const float* __restrict__ W11b, const float* __restrict__ W12b,
    const float* __restrict__ W13b, const float* __restrict__ n3g,
    const float* __restrict__ n3b, float* __restrict__ outE) {
  __shared__ __align__(16) unsigned short sA[128 * LDA];
  __shared__ float sStat[128][2][2];

  const int tid = threadIdx.x;
  const int lane = tid & 63;
  const int w = tid >> 6;
  const int wr = w >> 1, wcid = w & 1;
  const int bid = (blockIdx.x & 7) * 512 + (blockIdx.x >> 3);  // XCD: one batch per XCD
  const int v0 = bid << 2;
  const int b = v0 >> 11;
  const int n0 = v0 & (N_ - 1);
  const int bBase = b * N_;
  const int rl = lane & 15;

  const unsigned short* W11c = wc + 81920;
  const unsigned short* W12c = wc + 131072;
  const unsigned short* W13c = wc + 147456;

  int jrow[4];
#pragma unroll
  for (int m = 0; m < 4; ++m) {
    const int row = wr * 64 + m * 16 + rl;
    const int g = row >> 5;
    int kk = row & 31; if (kk >= K_) kk = K_ - 1;
    jrow[m] = Eidx[(bBase + n0 + g) * K_ + kk];
  }

  f32x4 acc[4][4];
  ZERO_ACC(acc)

  gemm_direct_bf16<384>([&](int m, int row) {
    return hV2c + (((size_t)(bBase + n0 + (row >> 5))) << 7);
  }, W11c, lane, wr, wcid, acc);
  gemm_direct_bf16<384>([&](int m, int row) {
    return hV2c + (((size_t)(bBase + jrow[m])) << 7);
  }, W11c + 128, lane, wr, wcid, acc);
  gemm_direct_f32<384>([&](int m, int row) {
    const int g = row >> 5;
    int kk = row & 31; if (kk >= K_) kk = K_ - 1;
    return hE + (((size_t)((bBase + n0 + g) * K_ + kk)) << 7);
  }, W11c + 256, lane, wr, wcid, acc);

  bias_gelu_store(acc, W11b, sA, lane, wr, wcid);
  __syncthreads();

  f32x4 acc2[4][4];
  ZERO_ACC(acc2)
  wave_gemm<128>(sA, W12c, lane, wr, wcid, acc2);
  __syncthreads();
  bias_gelu_store(acc2, W12b, sA, lane, wr, wcid);
  __syncthreads();

  f32x4 acc3[4][4];
  ZERO_ACC(acc3)
  wave_gemm<128>(sA, W13c, lane, wr, wcid, acc3);

  // register epilogue: x = acc3 + bias + hE residual; LN3; store
  float gc[4], bc[4], wb[4];
#pragma unroll
  for (int n = 0; n < 4; ++n) {
    const int col = wcid * 64 + n * 16 + rl;
    gc[n] = n3g[col]; bc[n] = n3b[col]; wb[n] = W13b[col];
  }
#pragma unroll
  for (int m = 0; m < 4; ++m) {
#pragma unroll
    for (int i = 0; i < 4; ++i) {
      const int row = wr * 64 + m * 16 + ((lane >> 4) << 2) + i;
      const int g = row >> 5, kk = row & 31;
      const bool valid = kk < K_;
      const float* er = hE + (((size_t)((bBase + n0 + g) * K_ + kk)) << 7) + wcid * 64 + rl;
      float s = 0.f, ss = 0.f;
#pragma unroll
      for (int n = 0; n < 4; ++n) {
        float x = acc3[m][n][i] + wb[n];
        if (valid) x += er[n * 16];
        acc3[m][n][i] = x;
        s += x; ss += x * x;
      }
#pragma unroll
      for (int o = 1; o <= 8; o <<= 1) { s += __shfl_xor(s, o); ss += __shfl_xor(ss, o); }
      if (rl == 0) { sStat[row][0][wcid] = s; sStat[row][1][wcid] = ss; }
    }
  }
  __syncthreads();
#pragma unroll
  for (int m = 0; m < 4; ++m) {
#pragma unroll
    for (int i = 0; i < 4; ++i) {
      const int row = wr * 64 + m * 16 + ((lane >> 4) << 2) + i;
      const int g = row >> 5, kk = row & 31;
      if (kk >= K_) continue;
      const float sum = sStat[row][0][0] + sStat[row][0][1];
      const float ssq = sStat[row][1][0] + sStat[row][1][1];
      const float mean = sum * (1.0f / 128.0f);
      const float inv = rsqrtf(ssq * (1.0f / 128.0f) - mean * mean + EPS_);
      float* dst = outE + (((size_t)((bBase + n0 + g) * K_ + kk)) << 7) + wcid * 64 + rl;
#pragma unroll
      for (int n = 0; n < 4; ++n)
        dst[n * 16] = gc[n] * (acc3[m][n][i] - mean) * inv + bc[n];
    }
  }
}

extern "C" void kernel_launch(void* const* d_in, const int* in_sizes, int n_in,
                              void* d_out, int out_size, void* d_ws, size_t ws_size,
                              hipStream_t stream) {
  const float* hV = (const float*)d_in[0];
  const float* hE = (const float*)d_in[1];
  const int* Eidx = (const int*)d_in[2];
  const float* maskV = (const float*)d_in[3];
  const float* mattend = (const float*)d_in[4];
  const float* W1w = (const float*)d_in[5];   const float* W1b = (const float*)d_in[6];
  const float* W2w = (const float*)d_in[7];   const float* W2b = (const float*)d_in[8];
  const float* W3w = (const float*)d_in[9];   const float* W3b = (const float*)d_in[10];
  const float* W11w = (const float*)d_in[11]; const float* W11b = (const float*)d_in[12];
  const float* W12w = (const float*)d_in[13]; const float* W12b = (const float*)d_in[14];
  const float* W13w = (const float*)d_in[15]; const float* W13b = (const float*)d_in[16];
  const float* n1g = (const float*)d_in[17];  const float* n1b = (const float*)d_in[18];
  const float* n2g = (const float*)d_in[19];  const float* n2b = (const float*)d_in[20];
  const float* n3g = (const float*)d_in[21];  const float* n3b = (const float*)d_in[22];
  const float* dinw = (const float*)d_in[23]; const float* dinb = (const float*)d_in[24];
  const float* doutw = (const float*)d_in[25]; const float* doutb = (const float*)d_in[26];

  unsigned short* wc   = (unsigned short*)d_ws;   // 294912 bf16 weights
  unsigned short* hV1b = wc + 294912;             // [B*N*H] bf16 (LN1 out)
  unsigned short* hV2c = hV1b + 2097152;          // [B*N*H] bf16 (LN2 out, masked)
  unsigned short* hVb  = hV2c + 2097152;          // [B*N*H] bf16 (input hV)
  // mandatory footprint: 589824 + 3*4194304 = 13,172,736 B (proven available)

  float* outV = (float*)d_out;
  float* outE = outV + (size_t)B_ * N_ * H_;

  prep<<<1152, 256, 0, stream>>>(W1w, W2w, W3w, W11w, W12w, W13w, dinw, doutw, wc);
  cvt8<<<1024, 256, 0, stream>>>(hV, hVb, 262144);
  k1<<<4096, 256, 0, stream>>>(hV, hVb, hE, Eidx, mattend, wc, W1b, W2b, W3b, n1g, n1b, hV1b);
  k2<<<256, 256, 0, stream>>>(hV1b, wc, dinb, doutb, n2g, n2b, maskV, outV, hV2c);
  k3<<<4096, 256, 0, stream>>>(hV2c, hE, Eidx, wc, W11b, W12b, W13b, n3g, n3b, outE);
}

// Round 4
// 466.420 us; speedup vs baseline: 1.7116x; 1.7116x over previous
//
#include <hip/hip_runtime.h>

#define B_ 8
#define N_ 2048
#define K_ 30
#define H_ 128
#define LDA 136
#define EPS_ 1e-5f

typedef __attribute__((ext_vector_type(8))) short short8;
typedef __attribute__((ext_vector_type(4))) float f32x4;

__device__ inline unsigned short f2bf(float f) {
  union { float f; unsigned u; } v; v.f = f;
  unsigned r = v.u + 0x7fffu + ((v.u >> 16) & 1u);
  return (unsigned short)(r >> 16);
}

__device__ inline float bf2f(unsigned short h) {
  union { unsigned u; float f; } v; v.u = ((unsigned)h) << 16; return v.f;
}

// tanh-form GELU: x * sigmoid(1.5957691*(x + 0.044715 x^3)); ~7 VALU incl 1 exp
__device__ inline float gelu_t(float x) {
  const float p = x * x;
  const float z = x * (1.5957691216057308f + 0.07135481627f * p);
  const float e = exp2f(z * -1.4426950408889634f);  // e^{-z}
  return x / (1.0f + e);
}

__device__ inline short8 pack8(float4 a, float4 b) {
  short8 o;
  o[0] = (short)f2bf(a.x); o[1] = (short)f2bf(a.y); o[2] = (short)f2bf(a.z); o[3] = (short)f2bf(a.w);
  o[4] = (short)f2bf(b.x); o[5] = (short)f2bf(b.y); o[6] = (short)f2bf(b.z); o[7] = (short)f2bf(b.w);
  return o;
}

// ---- 64-row wave GEMM: A = sA[64][LDA] (LDS bf16), B = W rows (global bf16,
// row-major [out][LDW]); wave covers out-cols cb + n*16 + (lane&15), n<NN ----
template<int LDW, int NN>
__device__ inline void gemm64(const unsigned short* __restrict__ sA,
                              const unsigned short* __restrict__ W,
                              int lane, int cb, f32x4 (&acc)[4][NN]) {
  const int rl = lane & 15;
  const int klo = (lane >> 4) << 3;
#pragma unroll
  for (int ks = 0; ks < 4; ++ks) {
    short8 a[4];
#pragma unroll
    for (int m = 0; m < 4; ++m)
      a[m] = *(const short8*)(sA + (m * 16 + rl) * LDA + ks * 32 + klo);
#pragma unroll
    for (int n = 0; n < NN; ++n) {
      const short8 b8 = *(const short8*)(W + (size_t)(cb + n * 16 + rl) * LDW + ks * 32 + klo);
#pragma unroll
      for (int m = 0; m < 4; ++m)
        acc[m][n] = __builtin_amdgcn_mfma_f32_16x16x32_bf16(a[m], b8, acc[m][n], 0, 0, 0);
    }
  }
}

#define ZERO2(A) \
  _Pragma("unroll") for (int m_ = 0; m_ < 4; ++m_) { A[m_][0] = (f32x4){0,0,0,0}; A[m_][1] = (f32x4){0,0,0,0}; }

// ---- prep: weights fp32 -> bf16 ----
__global__ __launch_bounds__(256) void prep(const float* __restrict__ w1, const float* __restrict__ w2,
                                            const float* __restrict__ w3, const float* __restrict__ w11,
                                            const float* __restrict__ w12, const float* __restrict__ w13,
                                            const float* __restrict__ din, const float* __restrict__ dout,
                                            unsigned short* __restrict__ dst) {
  const int i = blockIdx.x * 256 + threadIdx.x;  // grid covers exactly 294912
  const float* s; int off;
  if (i < 49152)       { s = w1;  off = 0; }
  else if (i < 65536)  { s = w2;  off = 49152; }
  else if (i < 81920)  { s = w3;  off = 65536; }
  else if (i < 131072) { s = w11; off = 81920; }
  else if (i < 147456) { s = w12; off = 131072; }
  else if (i < 163840) { s = w13; off = 147456; }
  else if (i < 229376) { s = din; off = 163840; }
  else                 { s = dout; off = 229376; }
  dst[i] = f2bf(s[i - off]);
}

// ---- pre-GEMM: Y = X @ [Wa|Wb]^T -> 256 cols (center|nbr halves) ----
// F32SRC: X fp32 (hV) else bf16 (hV2c). Yc/Yn may be the same buffer (stride 256)
// or split (stride 128 each) selected by SPLIT.
template<bool F32SRC, bool SPLIT>
__global__ __launch_bounds__(256) void preY(const void* __restrict__ Xv,
                                            const unsigned short* __restrict__ Wbase,
                                            unsigned short* __restrict__ Yc,
                                            unsigned short* __restrict__ Yn) {
  __shared__ __align__(16) unsigned short sA[64 * LDA];
  const int tid = threadIdx.x;
  const int lane = tid & 63;
  const int w = tid >> 6;
  const int rows = blockIdx.x << 6;
  const int rl = lane & 15;
  const int h4 = (lane >> 4) << 2;

  if (F32SRC) {
    const float* X = (const float*)Xv;
    for (int t = tid; t < 1024; t += 256) {
      const int r = t >> 4, seg = t & 15;
      const float* src = X + (((size_t)(rows + r)) << 7) + seg * 8;
      *(short8*)(sA + r * LDA + seg * 8) = pack8(*(const float4*)src, *(const float4*)(src + 4));
    }
  } else {
    const unsigned short* X = (const unsigned short*)Xv;
    for (int t = tid; t < 1024; t += 256) {
      const int r = t >> 4, seg = t & 15;
      *(short8*)(sA + r * LDA + seg * 8) =
          *(const short8*)(X + (((size_t)(rows + r)) << 7) + seg * 8);
    }
  }
  __syncthreads();

  const int half = w >> 1;            // 0: center (Wa), 1: nbr (Wb)
  const int cb = (w & 1) * 64;
  f32x4 acc[4][4];
#pragma unroll
  for (int m = 0; m < 4; ++m)
#pragma unroll
    for (int n = 0; n < 4; ++n) acc[m][n] = (f32x4){0, 0, 0, 0};
  gemm64<384, 4>(sA, Wbase + half * 128, lane, cb, acc);

  unsigned short* Y = half ? Yn : Yc;
  const int stride = SPLIT ? 128 : 256;
  const int coff = SPLIT ? 0 : half * 128;
#pragma unroll
  for (int n = 0; n < 4; ++n) {
    const int col = coff + cb + n * 16 + rl;
#pragma unroll
    for (int m = 0; m < 4; ++m)
#pragma unroll
      for (int i = 0; i < 4; ++i)
        Y[(size_t)(rows + m * 16 + h4 + i) * stride + col] = f2bf(acc[m][n][i]);
  }
}

// ---- k1: per-edge MLP (K=128 edge part) + masked k-sum + LN1 -> hV1b; side-writes hEb ----
__global__ __launch_bounds__(256, 4) void k1(
    const float* __restrict__ hV, const float* __restrict__ hE,
    const int* __restrict__ Eidx, const float* __restrict__ mattend,
    const unsigned short* __restrict__ wc, const unsigned short* __restrict__ Y1,
    const float* __restrict__ W1b, const float* __restrict__ W2b,
    const float* __restrict__ W3b, const float* __restrict__ n1g,
    const float* __restrict__ n1b, unsigned short* __restrict__ hV1b,
    float* __restrict__ outE) {
  __shared__ __align__(16) unsigned short sE[64 * LDA];  // hE bf16 (stays intact)
  __shared__ __align__(16) unsigned short sG[64 * LDA];  // Yn gather -> X1 -> X2
  __shared__ unsigned short sYc[2 * 128];
  __shared__ float sMask[64];
  __shared__ float sRed[2][128];

  const int tid = threadIdx.x;
  const int lane = tid & 63;
  const int w = tid >> 6;
  const int rl = lane & 15;
  const int h4 = (lane >> 4) << 2;
  const int bid = (blockIdx.x & 7) * 1024 + (blockIdx.x >> 3);  // 1 batch per XCD
  const int v0 = bid << 1;
  const int b = v0 >> 11;
  const int n0 = v0 & (N_ - 1);
  const int bBase = b * N_;

  const unsigned short* W1c = wc;          // [128][384]
  const unsigned short* W2c = wc + 49152;  // [128][128]
  const unsigned short* W3c = wc + 65536;  // [128][128]

  // stage hE rows (fp32->bf16) + side-write bf16 copy into outE rows' 2nd half
  for (int t = tid; t < 1024; t += 256) {
    const int r = t >> 4, seg = t & 15;
    const int g = r >> 5, kk = r & 31;
    const int kc = kk < K_ ? kk : K_ - 1;
    const size_t e = (size_t)(bBase + n0 + g) * K_ + kc;
    const float* src = hE + (e << 7) + seg * 8;
    const short8 o = pack8(*(const float4*)src, *(const float4*)(src + 4));
    *(short8*)(sE + r * LDA + seg * 8) = o;
    if (kk < K_)
      *(short8*)((unsigned short*)(outE + (e << 7)) + 128 + seg * 8) = o;
  }
  // stage gathered Yn rows
  for (int t = tid; t < 1024; t += 256) {
    const int r = t >> 4, seg = t & 15;
    const int g = r >> 5;
    int kk = r & 31; if (kk >= K_) kk = K_ - 1;
    const int j = Eidx[(bBase + n0 + g) * K_ + kk];
    *(short8*)(sG + r * LDA + seg * 8) =
        *(const short8*)(Y1 + (size_t)(bBase + j) * 256 + 128 + seg * 8);
  }
  // stage center Yc rows + mask
  {
    const int g = tid >> 7, c = tid & 127;
    sYc[g * 128 + c] = Y1[(size_t)(bBase + n0 + g) * 256 + c];
  }
  if (tid < 64) {
    const int g = tid >> 5, kk = tid & 31;
    sMask[tid] = (kk < K_) ? mattend[(bBase + n0 + g) * K_ + kk] : 0.f;
  }
  __syncthreads();

  f32x4 acc[4][2];
  ZERO2(acc)
  gemm64<384, 2>(sE, W1c + 256, lane, w * 32, acc);

  // combine: + b1 + Yc + Yn, gelu -> X1 (in place into sG; per-lane-owned cells)
#pragma unroll
  for (int n = 0; n < 2; ++n) {
    const int f = w * 32 + n * 16 + rl;
    const float bb = W1b[f];
#pragma unroll
    for (int m = 0; m < 4; ++m)
#pragma unroll
      for (int i = 0; i < 4; ++i) {
        const int e = m * 16 + h4 + i;
        const float x = acc[m][n][i] + bb + bf2f(sYc[(e >> 5) * 128 + f]) + bf2f(sG[e * LDA + f]);
        sG[e * LDA + f] = f2bf(gelu_t(x));
      }
  }
  __syncthreads();

  f32x4 acc2[4][2];
  ZERO2(acc2)
  gemm64<128, 2>(sG, W2c, lane, w * 32, acc2);
  __syncthreads();
#pragma unroll
  for (int n = 0; n < 2; ++n) {
    const int f = w * 32 + n * 16 + rl;
    const float bb = W2b[f];
#pragma unroll
    for (int m = 0; m < 4; ++m)
#pragma unroll
      for (int i = 0; i < 4; ++i) {
        const int e = m * 16 + h4 + i;
        sG[e * LDA + f] = f2bf(gelu_t(acc2[m][n][i] + bb));
      }
  }
  __syncthreads();

  f32x4 acc3[4][2];
  ZERO2(acc3)
  gemm64<128, 2>(sG, W3c, lane, w * 32, acc3);

  // masked k-sum over the 32 rows of each node
#pragma unroll
  for (int n = 0; n < 2; ++n) {
    const int f = w * 32 + n * 16 + rl;
    const float bb = W3b[f];
#pragma unroll
    for (int g = 0; g < 2; ++g) {
      float s = 0.f;
#pragma unroll
      for (int mm = 0; mm < 2; ++mm) {
        const int m = g * 2 + mm;
#pragma unroll
        for (int i = 0; i < 4; ++i) {
          const int e = m * 16 + h4 + i;
          s += (acc3[m][n][i] + bb) * sMask[e];
        }
      }
      s += __shfl_xor(s, 16);
      s += __shfl_xor(s, 32);
      if (lane < 16) sRed[g][f] = s;
    }
  }
  __syncthreads();

  // residual + LN1 (waves 0,1 -> nodes 0,1)
  if (w < 2) {
    const size_t base = ((size_t)(bBase + n0 + w)) << 7;
    const float x0 = hV[base + lane] + sRed[w][lane] * (1.0f / 30.0f);
    const float x1 = hV[base + 64 + lane] + sRed[w][64 + lane] * (1.0f / 30.0f);
    float s = x0 + x1;
#pragma unroll
    for (int o = 1; o < 64; o <<= 1) s += __shfl_xor(s, o);
    const float mean = s * (1.0f / 128.0f);
    const float d0 = x0 - mean, d1 = x1 - mean;
    float vs = d0 * d0 + d1 * d1;
#pragma unroll
    for (int o = 1; o < 64; o <<= 1) vs += __shfl_xor(vs, o);
    const float inv = rsqrtf(vs * (1.0f / 128.0f) + EPS_);
    hV1b[base + lane] = f2bf(n1g[lane] * (d0 * inv) + n1b[lane]);
    hV1b[base + 64 + lane] = f2bf(n1g[64 + lane] * (d1 * inv) + n1b[64 + lane]);
  }
}

// ---- k2: FFN + LN2 + mask_V -> outV (fp32) and hV2c (bf16); 64 rows/block ----
__global__ __launch_bounds__(256) void k2(
    const unsigned short* __restrict__ hV1b, const unsigned short* __restrict__ wc,
    const float* __restrict__ dinb, const float* __restrict__ doutb,
    const float* __restrict__ n2g, const float* __restrict__ n2b,
    const float* __restrict__ maskV, float* __restrict__ outV,
    unsigned short* __restrict__ hV2c) {
  __shared__ __align__(16) unsigned short sT[64 * LDA];
  __shared__ float sStat[64][2][4];

  const int tid = threadIdx.x;
  const int lane = tid & 63;
  const int w = tid >> 6;
  const int rowbase = blockIdx.x << 6;
  const int rl = lane & 15;
  const int klo = (lane >> 4) << 3;

  const unsigned short* dinc = wc + 163840;   // [512][128]
  const unsigned short* doutc = wc + 229376;  // [128][512]

  short8 a[4][4];
#pragma unroll
  for (int ks = 0; ks < 4; ++ks)
#pragma unroll
    for (int m = 0; m < 4; ++m)
      a[ks][m] = *(const short8*)(hV1b + (((size_t)(rowbase + m * 16 + rl)) << 7) + ks * 32 + klo);

  f32x4 acc2[4][2];
  ZERO2(acc2)

  for (int c = 0; c < 4; ++c) {
    f32x4 acc1[4][2];
    ZERO2(acc1)
#pragma unroll
    for (int ks = 0; ks < 4; ++ks)
#pragma unroll
      for (int n = 0; n < 2; ++n) {
        const short8 b8 = *(const short8*)(dinc + (size_t)(c * 128 + w * 32 + n * 16 + rl) * 128 + ks * 32 + klo);
#pragma unroll
        for (int m = 0; m < 4; ++m)
          acc1[m][n] = __builtin_amdgcn_mfma_f32_16x16x32_bf16(a[ks][m], b8, acc1[m][n], 0, 0, 0);
      }
    __syncthreads();
#pragma unroll
    for (int n = 0; n < 2; ++n) {
      const int col = w * 32 + n * 16 + rl;
      const float bb = dinb[c * 128 + col];
#pragma unroll
      for (int m = 0; m < 4; ++m)
#pragma unroll
        for (int i = 0; i < 4; ++i)
          sT[(m * 16 + ((lane >> 4) << 2) + i) * LDA + col] = f2bf(gelu_t(acc1[m][n][i] + bb));
    }
    __syncthreads();
#pragma unroll
    for (int ks = 0; ks < 4; ++ks) {
      short8 a2[4];
#pragma unroll
      for (int m = 0; m < 4; ++m)
        a2[m] = *(const short8*)(sT + (m * 16 + rl) * LDA + ks * 32 + klo);
#pragma unroll
      for (int n = 0; n < 2; ++n) {
        const short8 b8 = *(const short8*)(doutc + (size_t)(w * 32 + n * 16 + rl) * 512 + c * 128 + ks * 32 + klo);
#pragma unroll
        for (int m = 0; m < 4; ++m)
          acc2[m][n] = __builtin_amdgcn_mfma_f32_16x16x32_bf16(a2[m], b8, acc2[m][n], 0, 0, 0);
      }
    }
  }

  float gc[2], bc[2], wb[2];
#pragma unroll
  for (int n = 0; n < 2; ++n) {
    const int col = w * 32 + n * 16 + rl;
    gc[n] = n2g[col]; bc[n] = n2b[col]; wb[n] = doutb[col];
  }
#pragma unroll
  for (int m = 0; m < 4; ++m) {
#pragma unroll
    for (int i = 0; i < 4; ++i) {
      const int row = m * 16 + ((lane >> 4) << 2) + i;
      const unsigned short* rr = hV1b + (((size_t)(rowbase + row)) << 7) + w * 32 + rl;
      float s = 0.f, ss = 0.f;
#pragma unroll
      for (int n = 0; n < 2; ++n) {
        float x = acc2[m][n][i] + wb[n] + bf2f(rr[n * 16]);
        acc2[m][n][i] = x;
        s += x; ss += x * x;
      }
#pragma unroll
      for (int o = 1; o <= 8; o <<= 1) { s += __shfl_xor(s, o); ss += __shfl_xor(ss, o); }
      if (rl == 0) { sStat[row][0][w] = s; sStat[row][1][w] = ss; }
    }
  }
  __syncthreads();
#pragma unroll
  for (int m = 0; m < 4; ++m) {
#pragma unroll
    for (int i = 0; i < 4; ++i) {
      const int row = m * 16 + ((lane >> 4) << 2) + i;
      const int grow = rowbase + row;
      const float sum = sStat[row][0][0] + sStat[row][0][1] + sStat[row][0][2] + sStat[row][0][3];
      const float ssq = sStat[row][1][0] + sStat[row][1][1] + sStat[row][1][2] + sStat[row][1][3];
      const float mean = sum * (1.0f / 128.0f);
      const float inv = rsqrtf(ssq * (1.0f / 128.0f) - mean * mean + EPS_);
      const float mv = maskV[grow];
      float* dst = outV + (((size_t)grow) << 7) + w * 32 + rl;
      unsigned short* dstc = hV2c + (((size_t)grow) << 7) + w * 32 + rl;
#pragma unroll
      for (int n = 0; n < 2; ++n) {
        const float y = (gc[n] * (acc2[m][n][i] - mean) * inv + bc[n]) * mv;
        dst[n * 16] = y;
        dstc[n * 16] = f2bf(y);
      }
    }
  }
}

// ---- k3: per-edge MLP + residual(hEb) + LN3 -> outE ----
__global__ __launch_bounds__(256, 4) void k3(
    const float* __restrict__ hE_unused, const int* __restrict__ Eidx,
    const unsigned short* __restrict__ wc,
    const unsigned short* __restrict__ Y2c, const unsigned short* __restrict__ Y2n,
    const float* __restrict__ W11b, const float* __restrict__ W12b,
    const float* __restrict__ W13b, const float* __restrict__ n3g,
    const float* __restrict__ n3b, float* __restrict__ outE) {
  __shared__ __align__(16) unsigned short sE[64 * LDA];  // hE bf16 (stays intact for residual)
  __shared__ __align__(16) unsigned short sG[64 * LDA];  // Yn gather -> X1 -> X2
  __shared__ unsigned short sYc[2 * 128];
  __shared__ float sStat[64][2][4];

  const int tid = threadIdx.x;
  const int lane = tid & 63;
  const int w = tid >> 6;
  const int rl = lane & 15;
  const int h4 = (lane >> 4) << 2;
  const int bid = (blockIdx.x & 7) * 1024 + (blockIdx.x >> 3);
  const int v0 = bid << 1;
  const int b = v0 >> 11;
  const int n0 = v0 & (N_ - 1);
  const int bBase = b * N_;

  const unsigned short* W11c = wc + 81920;
  const unsigned short* W12c = wc + 131072;
  const unsigned short* W13c = wc + 147456;

  // stage hE bf16 rows from outE second halves (written by k1)
  for (int t = tid; t < 1024; t += 256) {
    const int r = t >> 4, seg = t & 15;
    const int g = r >> 5;
    int kk = r & 31; if (kk >= K_) kk = K_ - 1;
    const size_t e = (size_t)(bBase + n0 + g) * K_ + kk;
    *(short8*)(sE + r * LDA + seg * 8) =
        *(const short8*)((const unsigned short*)(outE + (e << 7)) + 128 + seg * 8);
  }
  // stage gathered Y2n rows
  for (int t = tid; t < 1024; t += 256) {
    const int r = t >> 4, seg = t & 15;
    const int g = r >> 5;
    int kk = r & 31; if (kk >= K_) kk = K_ - 1;
    const int j = Eidx[(bBase + n0 + g) * K_ + kk];
    *(short8*)(sG + r * LDA + seg * 8) =
        *(const short8*)(Y2n + (size_t)(bBase + j) * 128 + seg * 8);
  }
  {
    const int g = tid >> 7, c = tid & 127;
    sYc[g * 128 + c] = Y2c[(size_t)(bBase + n0 + g) * 128 + c];
  }
  __syncthreads();

  f32x4 acc[4][2];
  ZERO2(acc)
  gemm64<384, 2>(sE, W11c + 256, lane, w * 32, acc);

#pragma unroll
  for (int n = 0; n < 2; ++n) {
    const int f = w * 32 + n * 16 + rl;
    const float bb = W11b[f];
#pragma unroll
    for (int m = 0; m < 4; ++m)
#pragma unroll
      for (int i = 0; i < 4; ++i) {
        const int e = m * 16 + h4 + i;
        const float x = acc[m][n][i] + bb + bf2f(sYc[(e >> 5) * 128 + f]) + bf2f(sG[e * LDA + f]);
        sG[e * LDA + f] = f2bf(gelu_t(x));
      }
  }
  __syncthreads();

  f32x4 acc2[4][2];
  ZERO2(acc2)
  gemm64<128, 2>(sG, W12c, lane, w * 32, acc2);
  __syncthreads();
#pragma unroll
  for (int n = 0; n < 2; ++n) {
    const int f = w * 32 + n * 16 + rl;
    const float bb = W12b[f];
#pragma unroll
    for (int m = 0; m < 4; ++m)
#pragma unroll
      for (int i = 0; i < 4; ++i) {
        const int e = m * 16 + h4 + i;
        sG[e * LDA + f] = f2bf(gelu_t(acc2[m][n][i] + bb));
      }
  }
  __syncthreads();

  f32x4 acc3[4][2];
  ZERO2(acc3)
  gemm64<128, 2>(sG, W13c, lane, w * 32, acc3);

  // epilogue: x = msg + b + hE(bf16, from sE); LN3 with 4-wave partials
  float gc[2], bc[2], wb[2];
#pragma unroll
  for (int n = 0; n < 2; ++n) {
    const int f = w * 32 + n * 16 + rl;
    gc[n] = n3g[f]; bc[n] = n3b[f]; wb[n] = W13b[f];
  }
#pragma unroll
  for (int m = 0; m < 4; ++m)
#pragma unroll
    for (int i = 0; i < 4; ++i) {
      const int e = m * 16 + h4 + i;
      float s = 0.f, ss = 0.f;
#pragma unroll
      for (int n = 0; n < 2; ++n) {
        const int f = w * 32 + n * 16 + rl;
        const float x = acc3[m][n][i] + wb[n] + bf2f(sE[e * LDA + f]);
        acc3[m][n][i] = x;
        s += x; ss += x * x;
      }
#pragma unroll
      for (int o = 1; o <= 8; o <<= 1) { s += __shfl_xor(s, o); ss += __shfl_xor(ss, o); }
      if (rl == 0) { sStat[e][0][w] = s; sStat[e][1][w] = ss; }
    }
  __syncthreads();
#pragma unroll
  for (int m = 0; m < 4; ++m)
#pragma unroll
    for (int i = 0; i < 4; ++i) {
      const int e = m * 16 + h4 + i;
      const int g = e >> 5, kk = e & 31;
      if (kk >= K_) continue;
      const float sum = sStat[e][0][0] + sStat[e][0][1] + sStat[e][0][2] + sStat[e][0][3];
      const float ssq = sStat[e][1][0] + sStat[e][1][1] + sStat[e][1][2] + sStat[e][1][3];
      const float mean = sum * (1.0f / 128.0f);
      const float inv = rsqrtf(ssq * (1.0f / 128.0f) - mean * mean + EPS_);
      float* dst = outE + (((size_t)((bBase + n0 + g) * K_ + kk)) << 7) + w * 32 + rl;
#pragma unroll
      for (int n = 0; n < 2; ++n)
        dst[n * 16] = gc[n] * (acc3[m][n][i] - mean) * inv + bc[n];
    }
}

extern "C" void kernel_launch(void* const* d_in, const int* in_sizes, int n_in,
                              void* d_out, int out_size, void* d_ws, size_t ws_size,
                              hipStream_t stream) {
  const float* hV = (const float*)d_in[0];
  const float* hE = (const float*)d_in[1];
  const int* Eidx = (const int*)d_in[2];
  const float* maskV = (const float*)d_in[3];
  const float* mattend = (const float*)d_in[4];
  const float* W1w = (const float*)d_in[5];   const float* W1b = (const float*)d_in[6];
  const float* W2w = (const float*)d_in[7];   const float* W2b = (const float*)d_in[8];
  const float* W3w = (const float*)d_in[9];   const float* W3b = (const float*)d_in[10];
  const float* W11w = (const float*)d_in[11]; const float* W11b = (const float*)d_in[12];
  const float* W12w = (const float*)d_in[13]; const float* W12b = (const float*)d_in[14];
  const float* W13w = (const float*)d_in[15]; const float* W13b = (const float*)d_in[16];
  const float* n1g = (const float*)d_in[17];  const float* n1b = (const float*)d_in[18];
  const float* n2g = (const float*)d_in[19];  const float* n2b = (const float*)d_in[20];
  const float* n3g = (const float*)d_in[21];  const float* n3b = (const float*)d_in[22];
  const float* dinw = (const float*)d_in[23]; const float* dinb = (const float*)d_in[24];
  const float* doutw = (const float*)d_in[25]; const float* doutb = (const float*)d_in[26];

  // ws layout (bytes), peak == proven 13,172,736:
  //   [0, 589824)          wc  (bf16 weights)
  //   [589824, 8978432)    Region1 (8 MB): Y1 (k1 phase) -> hV2c (first half) + Y2c (second half)
  //   [8978432, 13172736)  Region2 (4 MB): hV1b (k1/k2) -> Y2n (k3 phase)
  unsigned short* wc   = (unsigned short*)d_ws;
  unsigned short* R1   = wc + 294912;
  unsigned short* R2   = R1 + 4194304;
  unsigned short* Y1   = R1;            // [BN][256] bf16
  unsigned short* hV1b = R2;            // [BN][128] bf16
  unsigned short* hV2c = R1;            // [BN][128] bf16 (Y1 dead after k1)
  unsigned short* Y2c  = R1 + 2097152;  // [BN][128] bf16
  unsigned short* Y2n  = R2;            // [BN][128] bf16 (hV1b dead after k2)

  float* outV = (float*)d_out;
  float* outE = outV + (size_t)B_ * N_ * H_;

  prep<<<1152, 256, 0, stream>>>(W1w, W2w, W3w, W11w, W12w, W13w, dinw, doutw, wc);
  preY<true, false><<<256, 256, 0, stream>>>(hV, wc, Y1, Y1);
  k1<<<8192, 256, 0, stream>>>(hV, hE, Eidx, mattend, wc, Y1,
                               W1b, W2b, W3b, n1g, n1b, hV1b, outE);
  k2<<<256, 256, 0, stream>>>(hV1b, wc, dinb, doutb, n2g, n2b, maskV, outV, hV2c);
  preY<false, true><<<256, 256, 0, stream>>>(hV2c, wc + 81920, Y2c, Y2n);
  k3<<<8192, 256, 0, stream>>>(hE, Eidx, wc, Y2c, Y2n,
                               W11b, W12b, W13b, n3g, n3b, outE);
}

// Round 7
// 460.598 us; speedup vs baseline: 1.7332x; 1.0126x over previous
//
#include <hip/hip_runtime.h>

#define B_ 8
#define N_ 2048
#define K_ 30
#define H_ 128
#define LDA 136
#define LDM 132
#define EPS_ 1e-5f

typedef __attribute__((ext_vector_type(8))) short short8;
typedef __attribute__((ext_vector_type(4))) float f32x4;

__device__ inline unsigned short f2bf(float f) {
  union { float f; unsigned u; } v; v.f = f;
  unsigned r = v.u + 0x7fffu + ((v.u >> 16) & 1u);
  return (unsigned short)(r >> 16);
}

__device__ inline float bf2f(unsigned short h) {
  union { unsigned u; float f; } v; v.u = ((unsigned)h) << 16; return v.f;
}

// pack 2 f32 -> 2 bf16 (RNE) in one instr
__device__ inline unsigned pkbf(float lo, float hi) {
  unsigned r;
  asm("v_cvt_pk_bf16_f32 %0, %1, %2" : "=v"(r) : "v"(lo), "v"(hi));
  return r;
}

// tanh-form GELU with fast rcp (validated via output 0 in R5/R6 through k2)
__device__ inline float gelu_t(float x) {
  const float p = x * x;
  const float z = x * (1.5957691216057308f + 0.07135481627f * p);
  const float e = exp2f(z * -1.4426950408889634f);  // e^{-z}
  return x * __builtin_amdgcn_rcpf(1.0f + e);
}

__device__ inline short8 pack8(float4 a, float4 b) {
  short8 o;
  o[0] = (short)f2bf(a.x); o[1] = (short)f2bf(a.y); o[2] = (short)f2bf(a.z); o[3] = (short)f2bf(a.w);
  o[4] = (short)f2bf(b.x); o[5] = (short)f2bf(b.y); o[6] = (short)f2bf(b.z); o[7] = (short)f2bf(b.w);
  return o;
}

// ---- swapped-operand GEMM: D[feature][edge] (used by k1) ----
template<int LDW>
__device__ inline void gemmT(const unsigned short* __restrict__ sA,
                             const unsigned short* __restrict__ W,
                             int lane, int cb, f32x4 (&acc)[4][2]) {
  const int rl = lane & 15;
  const int klo = (lane >> 4) << 3;
#pragma unroll
  for (int ks = 0; ks < 4; ++ks) {
    short8 wf[2];
#pragma unroll
    for (int fn = 0; fn < 2; ++fn)
      wf[fn] = *(const short8*)(W + (size_t)(cb + fn * 16 + rl) * LDW + ks * 32 + klo);
#pragma unroll
    for (int et = 0; et < 4; ++et) {
      const short8 ef = *(const short8*)(sA + (et * 16 + rl) * LDA + ks * 32 + klo);
      acc[et][0] = __builtin_amdgcn_mfma_f32_16x16x32_bf16(wf[0], ef, acc[et][0], 0, 0, 0);
      acc[et][1] = __builtin_amdgcn_mfma_f32_16x16x32_bf16(wf[1], ef, acc[et][1], 0, 0, 0);
    }
  }
}

#define ZERO42(A) \
  _Pragma("unroll") for (int e_ = 0; e_ < 4; ++e_) { A[e_][0] = (f32x4){0,0,0,0}; A[e_][1] = (f32x4){0,0,0,0}; }

// ---- old-layout 64-row wave GEMM (preY + k3): D[edge/node-row][feature] ----
template<int LDW, int NN>
__device__ inline void gemm64(const unsigned short* __restrict__ sA,
                              const unsigned short* __restrict__ W,
                              int lane, int cb, f32x4 (&acc)[4][NN]) {
  const int rl = lane & 15;
  const int klo = (lane >> 4) << 3;
#pragma unroll
  for (int ks = 0; ks < 4; ++ks) {
    short8 a[4];
#pragma unroll
    for (int m = 0; m < 4; ++m)
      a[m] = *(const short8*)(sA + (m * 16 + rl) * LDA + ks * 32 + klo);
#pragma unroll
    for (int n = 0; n < NN; ++n) {
      const short8 b8 = *(const short8*)(W + (size_t)(cb + n * 16 + rl) * LDW + ks * 32 + klo);
#pragma unroll
      for (int m = 0; m < 4; ++m)
        acc[m][n] = __builtin_amdgcn_mfma_f32_16x16x32_bf16(a[m], b8, acc[m][n], 0, 0, 0);
    }
  }
}

// ---- prep: weights fp32 -> bf16 ----
__global__ __launch_bounds__(256) void prep(const float* __restrict__ w1, const float* __restrict__ w2,
                                            const float* __restrict__ w3, const float* __restrict__ w11,
                                            const float* __restrict__ w12, const float* __restrict__ w13,
                                            const float* __restrict__ din, const float* __restrict__ dout,
                                            unsigned short* __restrict__ dst) {
  const int i = blockIdx.x * 256 + threadIdx.x;  // grid covers exactly 294912
  const float* s; int off;
  if (i < 49152)       { s = w1;  off = 0; }
  else if (i < 65536)  { s = w2;  off = 49152; }
  else if (i < 81920)  { s = w3;  off = 65536; }
  else if (i < 131072) { s = w11; off = 81920; }
  else if (i < 147456) { s = w12; off = 131072; }
  else if (i < 163840) { s = w13; off = 147456; }
  else if (i < 229376) { s = din; off = 163840; }
  else                 { s = dout; off = 229376; }
  dst[i] = f2bf(s[i - off]);
}

// ---- pre-GEMM: Y = X @ [Wa|Wb]^T -> 256 cols (center|nbr halves) ----
template<bool F32SRC, bool SPLIT>
__global__ __launch_bounds__(256) void preY(const void* __restrict__ Xv,
                                            const unsigned short* __restrict__ Wbase,
                                            unsigned short* __restrict__ Yc,
                                            unsigned short* __restrict__ Yn) {
  __shared__ __align__(16) unsigned short sA[64 * LDA];
  const int tid = threadIdx.x;
  const int lane = tid & 63;
  const int w = tid >> 6;
  const int rows = blockIdx.x << 6;
  const int rl = lane & 15;
  const int h4 = (lane >> 4) << 2;

  if (F32SRC) {
    const float* X = (const float*)Xv;
    for (int t = tid; t < 1024; t += 256) {
      const int r = t >> 4, seg = t & 15;
      const float* src = X + (((size_t)(rows + r)) << 7) + seg * 8;
      *(short8*)(sA + r * LDA + seg * 8) = pack8(*(const float4*)src, *(const float4*)(src + 4));
    }
  } else {
    const unsigned short* X = (const unsigned short*)Xv;
    for (int t = tid; t < 1024; t += 256) {
      const int r = t >> 4, seg = t & 15;
      *(short8*)(sA + r * LDA + seg * 8) =
          *(const short8*)(X + (((size_t)(rows + r)) << 7) + seg * 8);
    }
  }
  __syncthreads();

  const int half = w >> 1;            // 0: center (Wa), 1: nbr (Wb)
  const int cb = (w & 1) * 64;
  f32x4 acc[4][4];
#pragma unroll
  for (int m = 0; m < 4; ++m)
#pragma unroll
    for (int n = 0; n < 4; ++n) acc[m][n] = (f32x4){0, 0, 0, 0};
  gemm64<384, 4>(sA, Wbase + half * 128, lane, cb, acc);

  unsigned short* Y = half ? Yn : Yc;
  const int stride = SPLIT ? 128 : 256;
  const int coff = SPLIT ? 0 : half * 128;
#pragma unroll
  for (int n = 0; n < 4; ++n) {
    const int col = coff + cb + n * 16 + rl;
#pragma unroll
    for (int m = 0; m < 4; ++m)
#pragma unroll
      for (int i = 0; i < 4; ++i)
        Y[(size_t)(rows + m * 16 + h4 + i) * stride + col] = f2bf(acc[m][n][i]);
  }
}

// ---- k1: per-edge MLP (hE part) + masked k-sum + LN1 -> hV1b; side-writes hEb stash ----
__global__ __launch_bounds__(256, 4) void k1(
    const float* __restrict__ hV, const float* __restrict__ hE,
    const int* __restrict__ Eidx, const float* __restrict__ mattend,
    const unsigned short* __restrict__ wc, const unsigned short* __restrict__ Y1,
    const float* __restrict__ W1b, const float* __restrict__ W2b,
    const float* __restrict__ W3b, const float* __restrict__ n1g,
    const float* __restrict__ n1b, unsigned short* __restrict__ hV1b,
    float* __restrict__ outE) {
  __shared__ __align__(16) unsigned short sBuf[2 * 64 * LDA];
  __shared__ __align__(16) unsigned short sYc[2 * 128];
  __shared__ float sMask[64];
  __shared__ float sRed[2][128];
  unsigned short* sE = sBuf;
  unsigned short* sG = sBuf + 64 * LDA;
  float* sM = (float*)sBuf;  // 64*LDM fp32 after GEMM3

  const int tid = threadIdx.x;
  const int lane = tid & 63;
  const int w = tid >> 6;
  const int rl = lane & 15;
  const int h4 = (lane >> 4) << 2;
  const int bid = (blockIdx.x & 7) * 1024 + (blockIdx.x >> 3);  // 1 batch per XCD
  const int v0 = bid << 1;
  const int b = v0 >> 11;
  const int n0 = v0 & (N_ - 1);
  const int bBase = b * N_;

  const unsigned short* W1c = wc;          // [128][384]
  const unsigned short* W2c = wc + 49152;  // [128][128]
  const unsigned short* W3c = wc + 65536;  // [128][128]

  // stage hE rows (fp32->bf16) + side-write bf16 stash into outE rows' 2nd half
  for (int t = tid; t < 1024; t += 256) {
    const int r = t >> 4, seg = t & 15;
    const int g = r >> 5, kk = r & 31;
    const int kc = kk < K_ ? kk : K_ - 1;
    const size_t e = (size_t)(bBase + n0 + g) * K_ + kc;
    const float* src = hE + (e << 7) + seg * 8;
    const short8 o = pack8(*(const float4*)src, *(const float4*)(src + 4));
    *(short8*)(sE + r * LDA + seg * 8) = o;
    if (kk < K_)
      *(short8*)((unsigned short*)(outE + (e << 7)) + 128 + seg * 8) = o;
  }
  // stage gathered Yn rows
  for (int t = tid; t < 1024; t += 256) {
    const int r = t >> 4, seg = t & 15;
    const int g = r >> 5;
    int kk = r & 31; if (kk >= K_) kk = K_ - 1;
    const int j = Eidx[(bBase + n0 + g) * K_ + kk];
    *(short8*)(sG + r * LDA + seg * 8) =
        *(const short8*)(Y1 + (size_t)(bBase + j) * 256 + 128 + seg * 8);
  }
  {
    const int g = tid >> 7, c = tid & 127;
    sYc[g * 128 + c] = Y1[(size_t)(bBase + n0 + g) * 256 + c];
  }
  if (tid < 64) {
    const int g = tid >> 5, kk = tid & 31;
    sMask[tid] = (kk < K_) ? mattend[(bBase + n0 + g) * K_ + kk] : 0.f;
  }
  __syncthreads();

  f32x4 acc[4][2];
  ZERO42(acc)
  gemmT<384>(sE, W1c + 256, lane, w * 32, acc);

  // combine: + b1 + Yc + Yn, gelu -> X1 into sG (lane-private 4-feature cells)
  {
    float4 b1v[2];
    b1v[0] = *(const float4*)(W1b + w * 32 + h4);
    b1v[1] = *(const float4*)(W1b + w * 32 + 16 + h4);
#pragma unroll
    for (int et = 0; et < 4; ++et) {
      const int e = et * 16 + rl;
      const int g = et >> 1;
#pragma unroll
      for (int fn = 0; fn < 2; ++fn) {
        const int f0 = w * 32 + fn * 16 + h4;
        const ushort4 yc = *(const ushort4*)(sYc + g * 128 + f0);
        const ushort4 yn = *(const ushort4*)(sG + e * LDA + f0);
        const float x0 = gelu_t(acc[et][fn][0] + b1v[fn].x + bf2f(yc.x) + bf2f(yn.x));
        const float x1 = gelu_t(acc[et][fn][1] + b1v[fn].y + bf2f(yc.y) + bf2f(yn.y));
        const float x2 = gelu_t(acc[et][fn][2] + b1v[fn].z + bf2f(yc.z) + bf2f(yn.z));
        const float x3 = gelu_t(acc[et][fn][3] + b1v[fn].w + bf2f(yc.w) + bf2f(yn.w));
        uint2 o; o.x = pkbf(x0, x1); o.y = pkbf(x2, x3);
        *(uint2*)(sG + e * LDA + f0) = o;
      }
    }
  }
  __syncthreads();

  f32x4 acc2[4][2];
  ZERO42(acc2)
  gemmT<128>(sG, W2c, lane, w * 32, acc2);
  __syncthreads();
  {
    float4 b2v[2];
    b2v[0] = *(const float4*)(W2b + w * 32 + h4);
    b2v[1] = *(const float4*)(W2b + w * 32 + 16 + h4);
#pragma unroll
    for (int et = 0; et < 4; ++et) {
      const int e = et * 16 + rl;
#pragma unroll
      for (int fn = 0; fn < 2; ++fn) {
        const int f0 = w * 32 + fn * 16 + h4;
        const float x0 = gelu_t(acc2[et][fn][0] + b2v[fn].x);
        const float x1 = gelu_t(acc2[et][fn][1] + b2v[fn].y);
        const float x2 = gelu_t(acc2[et][fn][2] + b2v[fn].z);
        const float x3 = gelu_t(acc2[et][fn][3] + b2v[fn].w);
        uint2 o; o.x = pkbf(x0, x1); o.y = pkbf(x2, x3);
        *(uint2*)(sG + e * LDA + f0) = o;
      }
    }
  }
  __syncthreads();

  f32x4 acc3[4][2];
  ZERO42(acc3)
  gemmT<128>(sG, W3c, lane, w * 32, acc3);
  __syncthreads();  // all LDS reads done; sBuf becomes sM (fp32 masked msgs)

  {
    float4 b3v[2];
    b3v[0] = *(const float4*)(W3b + w * 32 + h4);
    b3v[1] = *(const float4*)(W3b + w * 32 + 16 + h4);
#pragma unroll
    for (int et = 0; et < 4; ++et) {
      const int e = et * 16 + rl;
      const float mk = sMask[e];
#pragma unroll
      for (int fn = 0; fn < 2; ++fn) {
        const int f0 = w * 32 + fn * 16 + h4;
        const float4 v = make_float4((acc3[et][fn][0] + b3v[fn].x) * mk,
                                     (acc3[et][fn][1] + b3v[fn].y) * mk,
                                     (acc3[et][fn][2] + b3v[fn].z) * mk,
                                     (acc3[et][fn][3] + b3v[fn].w) * mk);
        *(float4*)(sM + e * LDM + f0) = v;
      }
    }
  }
  __syncthreads();

  // column sums over k (fp32), then LN1
  {
    const int g = tid >> 7, f = tid & 127;
    float s = 0.f;
#pragma unroll
    for (int kk = 0; kk < 32; ++kk) s += sM[(g * 32 + kk) * LDM + f];
    sRed[g][f] = s;
  }
  __syncthreads();

  if (w < 2) {
    const size_t base = ((size_t)(bBase + n0 + w)) << 7;
    const float x0 = hV[base + lane] + sRed[w][lane] * (1.0f / 30.0f);
    const float x1 = hV[base + 64 + lane] + sRed[w][64 + lane] * (1.0f / 30.0f);
    float s = x0 + x1;
#pragma unroll
    for (int o = 1; o < 64; o <<= 1) s += __shfl_xor(s, o);
    const float mean = s * (1.0f / 128.0f);
    const float d0 = x0 - mean, d1 = x1 - mean;
    float vs = d0 * d0 + d1 * d1;
#pragma unroll
    for (int o = 1; o < 64; o <<= 1) vs += __shfl_xor(vs, o);
    const float inv = rsqrtf(vs * (1.0f / 128.0f) + EPS_);
    hV1b[base + lane] = f2bf(n1g[lane] * (d0 * inv) + n1b[lane]);
    hV1b[base + 64 + lane] = f2bf(n1g[64 + lane] * (d1 * inv) + n1b[64 + lane]);
  }
}

// ---- k2: FFN + LN2 + mask_V -> outV (fp32) and hV2c (bf16); 16 rows/block ----
__global__ __launch_bounds__(256) void k2(
    const unsigned short* __restrict__ hV1b, const unsigned short* __restrict__ wc,
    const float* __restrict__ dinb, const float* __restrict__ doutb,
    const float* __restrict__ n2g, const float* __restrict__ n2b,
    const float* __restrict__ maskV, float* __restrict__ outV,
    unsigned short* __restrict__ hV2c) {
  __shared__ __align__(16) unsigned short sT[16 * LDA];
  __shared__ float sStat[16][2][4];

  const int tid = threadIdx.x;
  const int lane = tid & 63;
  const int w = tid >> 6;
  const int rl = lane & 15;
  const int h4 = (lane >> 4) << 2;
  const int klo = (lane >> 4) << 3;
  const int rowbase = blockIdx.x << 4;

  const unsigned short* dinc = wc + 163840;   // [512][128]
  const unsigned short* doutc = wc + 229376;  // [128][512]

  short8 ef[4];
#pragma unroll
  for (int ks = 0; ks < 4; ++ks)
    ef[ks] = *(const short8*)(hV1b + (((size_t)(rowbase + rl)) << 7) + ks * 32 + klo);

  f32x4 acc2[2];
  acc2[0] = (f32x4){0, 0, 0, 0}; acc2[1] = (f32x4){0, 0, 0, 0};

  for (int c = 0; c < 4; ++c) {
    f32x4 acc1[2];
    acc1[0] = (f32x4){0, 0, 0, 0}; acc1[1] = (f32x4){0, 0, 0, 0};
#pragma unroll
    for (int ks = 0; ks < 4; ++ks)
#pragma unroll
      for (int fn = 0; fn < 2; ++fn) {
        const short8 wf = *(const short8*)(dinc + (size_t)(c * 128 + w * 32 + fn * 16 + rl) * 128 + ks * 32 + klo);
        acc1[fn] = __builtin_amdgcn_mfma_f32_16x16x32_bf16(wf, ef[ks], acc1[fn], 0, 0, 0);
      }
    __syncthreads();  // previous chunk's GEMM2 reads of sT done
    {
      float4 db[2];
      db[0] = *(const float4*)(dinb + c * 128 + w * 32 + h4);
      db[1] = *(const float4*)(dinb + c * 128 + w * 32 + 16 + h4);
#pragma unroll
      for (int fn = 0; fn < 2; ++fn) {
        const int f0 = w * 32 + fn * 16 + h4;
        const float x0 = gelu_t(acc1[fn][0] + db[fn].x);
        const float x1 = gelu_t(acc1[fn][1] + db[fn].y);
        const float x2 = gelu_t(acc1[fn][2] + db[fn].z);
        const float x3 = gelu_t(acc1[fn][3] + db[fn].w);
        uint2 o; o.x = pkbf(x0, x1); o.y = pkbf(x2, x3);
        *(uint2*)(sT + rl * LDA + f0) = o;
      }
    }
    __syncthreads();
#pragma unroll
    for (int ks = 0; ks < 4; ++ks) {
      const short8 xf = *(const short8*)(sT + rl * LDA + ks * 32 + klo);
#pragma unroll
      for (int fn = 0; fn < 2; ++fn) {
        const short8 wf2 = *(const short8*)(doutc + (size_t)(w * 32 + fn * 16 + rl) * 512 + c * 128 + ks * 32 + klo);
        acc2[fn] = __builtin_amdgcn_mfma_f32_16x16x32_bf16(wf2, xf, acc2[fn], 0, 0, 0);
      }
    }
  }

  // epilogue: lane owns row rl, features f0..f0+3
  const int row = rl;
  const int grow = rowbase + row;
  {
    float4 wbv[2];
    wbv[0] = *(const float4*)(doutb + w * 32 + h4);
    wbv[1] = *(const float4*)(doutb + w * 32 + 16 + h4);
    float s = 0.f, ss = 0.f;
#pragma unroll
    for (int fn = 0; fn < 2; ++fn) {
      const int f0 = w * 32 + fn * 16 + h4;
      const ushort4 rr = *(const ushort4*)(hV1b + (((size_t)grow) << 7) + f0);
      const float x0 = acc2[fn][0] + wbv[fn].x + bf2f(rr.x);
      const float x1 = acc2[fn][1] + wbv[fn].y + bf2f(rr.y);
      const float x2 = acc2[fn][2] + wbv[fn].z + bf2f(rr.z);
      const float x3 = acc2[fn][3] + wbv[fn].w + bf2f(rr.w);
      acc2[fn] = (f32x4){x0, x1, x2, x3};
      s += x0 + x1 + x2 + x3;
      ss += x0 * x0 + x1 * x1 + x2 * x2 + x3 * x3;
    }
    s += __shfl_xor(s, 16); s += __shfl_xor(s, 32);
    ss += __shfl_xor(ss, 16); ss += __shfl_xor(ss, 32);
    if (lane < 16) { sStat[row][0][w] = s; sStat[row][1][w] = ss; }
  }
  __syncthreads();
  {
    const float sum = sStat[row][0][0] + sStat[row][0][1] + sStat[row][0][2] + sStat[row][0][3];
    const float ssq = sStat[row][1][0] + sStat[row][1][1] + sStat[row][1][2] + sStat[row][1][3];
    const float mean = sum * (1.0f / 128.0f);
    const float inv = rsqrtf(ssq * (1.0f / 128.0f) - mean * mean + EPS_);
    const float mv = maskV[grow];
#pragma unroll
    for (int fn = 0; fn < 2; ++fn) {
      const int f0 = w * 32 + fn * 16 + h4;
      const float4 gv = *(const float4*)(n2g + f0);
      const float4 bv = *(const float4*)(n2b + f0);
      const float y0 = (gv.x * (acc2[fn][0] - mean) * inv + bv.x) * mv;
      const float y1 = (gv.y * (acc2[fn][1] - mean) * inv + bv.y) * mv;
      const float y2 = (gv.z * (acc2[fn][2] - mean) * inv + bv.z) * mv;
      const float y3 = (gv.w * (acc2[fn][3] - mean) * inv + bv.w) * mv;
      *(float4*)(outV + (((size_t)grow) << 7) + f0) = make_float4(y0, y1, y2, y3);
      uint2 o; o.x = pkbf(y0, y1); o.y = pkbf(y2, y3);
      *(uint2*)(hV2c + (((size_t)grow) << 7) + f0) = o;
    }
  }
}

// ---- k3: edge MLP + residual + LN3 -> outE (VERBATIM R4-passing version) ----
__global__ __launch_bounds__(256, 4) void k3(
    const int* __restrict__ Eidx, const unsigned short* __restrict__ wc,
    const unsigned short* __restrict__ Y2c, const unsigned short* __restrict__ Y2n,
    const float* __restrict__ W11b, const float* __restrict__ W12b,
    const float* __restrict__ W13b, const float* __restrict__ n3g,
    const float* __restrict__ n3b, float* __restrict__ outE) {
  __shared__ __align__(16) unsigned short sE[64 * LDA];  // hE bf16 (stays intact for residual)
  __shared__ __align__(16) unsigned short sG[64 * LDA];  // Yn gather -> X1 -> X2
  __shared__ unsigned short sYc[2 * 128];
  __shared__ float sStat[64][2][4];

  const int tid = threadIdx.x;
  const int lane = tid & 63;
  const int w = tid >> 6;
  const int rl = lane & 15;
  const int h4 = (lane >> 4) << 2;
  const int bid = (blockIdx.x & 7) * 1024 + (blockIdx.x >> 3);
  const int v0 = bid << 1;
  const int b = v0 >> 11;
  const int n0 = v0 & (N_ - 1);
  const int bBase = b * N_;

  const unsigned short* W11c = wc + 81920;
  const unsigned short* W12c = wc + 131072;
  const unsigned short* W13c = wc + 147456;

  // stage hE bf16 rows from outE second halves (written by k1)
  for (int t = tid; t < 1024; t += 256) {
    const int r = t >> 4, seg = t & 15;
    const int g = r >> 5;
    int kk = r & 31; if (kk >= K_) kk = K_ - 1;
    const size_t e = (size_t)(bBase + n0 + g) * K_ + kk;
    *(short8*)(sE + r * LDA + seg * 8) =
        *(const short8*)((const unsigned short*)(outE + (e << 7)) + 128 + seg * 8);
  }
  // stage gathered Y2n rows
  for (int t = tid; t < 1024; t += 256) {
    const int r = t >> 4, seg = t & 15;
    const int g = r >> 5;
    int kk = r & 31; if (kk >= K_) kk = K_ - 1;
    const int j = Eidx[(bBase + n0 + g) * K_ + kk];
    *(short8*)(sG + r * LDA + seg * 8) =
        *(const short8*)(Y2n + (size_t)(bBase + j) * 128 + seg * 8);
  }
  {
    const int g = tid >> 7, c = tid & 127;
    sYc[g * 128 + c] = Y2c[(size_t)(bBase + n0 + g) * 128 + c];
  }
  __syncthreads();

  f32x4 acc[4][2];
  ZERO42(acc)
  gemm64<384, 2>(sE, W11c + 256, lane, w * 32, acc);

#pragma unroll
  for (int n = 0; n < 2; ++n) {
    const int f = w * 32 + n * 16 + rl;
    const float bb = W11b[f];
#pragma unroll
    for (int m = 0; m < 4; ++m)
#pragma unroll
      for (int i = 0; i < 4; ++i) {
        const int e = m * 16 + h4 + i;
        const float x = acc[m][n][i] + bb + bf2f(sYc[(e >> 5) * 128 + f]) + bf2f(sG[e * LDA + f]);
        sG[e * LDA + f] = f2bf(gelu_t(x));
      }
  }
  __syncthreads();

  f32x4 acc2[4][2];
  ZERO42(acc2)
  gemm64<128, 2>(sG, W12c, lane, w * 32, acc2);
  __syncthreads();
#pragma unroll
  for (int n = 0; n < 2; ++n) {
    const int f = w * 32 + n * 16 + rl;
    const float bb = W12b[f];
#pragma unroll
    for (int m = 0; m < 4; ++m)
#pragma unroll
      for (int i = 0; i < 4; ++i) {
        const int e = m * 16 + h4 + i;
        sG[e * LDA + f] = f2bf(gelu_t(acc2[m][n][i] + bb));
      }
  }
  __syncthreads();

  f32x4 acc3[4][2];
  ZERO42(acc3)
  gemm64<128, 2>(sG, W13c, lane, w * 32, acc3);

  // epilogue: x = msg + b + hE(bf16 from sE); LN3 with 4-wave partials
  float gc[2], bc[2], wb[2];
#pragma unroll
  for (int n = 0; n < 2; ++n) {
    const int f = w * 32 + n * 16 + rl;
    gc[n] = n3g[f]; bc[n] = n3b[f]; wb[n] = W13b[f];
  }
#pragma unroll
  for (int m = 0; m < 4; ++m)
#pragma unroll
    for (int i = 0; i < 4; ++i) {
      const int e = m * 16 + h4 + i;
      float s = 0.f, ss = 0.f;
#pragma unroll
      for (int n = 0; n < 2; ++n) {
        const int f = w * 32 + n * 16 + rl;
        const float x = acc3[m][n][i] + wb[n] + bf2f(sE[e * LDA + f]);
        acc3[m][n][i] = x;
        s += x; ss += x * x;
      }
#pragma unroll
      for (int o = 1; o <= 8; o <<= 1) { s += __shfl_xor(s, o); ss += __shfl_xor(ss, o); }
      if (rl == 0) { sStat[e][0][w] = s; sStat[e][1][w] = ss; }
    }
  __syncthreads();
#pragma unroll
  for (int m = 0; m < 4; ++m)
#pragma unroll
    for (int i = 0; i < 4; ++i) {
      const int e = m * 16 + h4 + i;
      const int g = e >> 5, kk = e & 31;
      if (kk >= K_) continue;
      const float sum = sStat[e][0][0] + sStat[e][0][1] + sStat[e][0][2] + sStat[e][0][3];
      const float ssq = sStat[e][1][0] + sStat[e][1][1] + sStat[e][1][2] + sStat[e][1][3];
      const float mean = sum * (1.0f / 128.0f);
      const float inv = rsqrtf(ssq * (1.0f / 128.0f) - mean * mean + EPS_);
      float* dst = outE + (((size_t)((bBase + n0 + g) * K_ + kk)) << 7) + w * 32 + rl;
#pragma unroll
      for (int n = 0; n < 2; ++n)
        dst[n * 16] = gc[n] * (acc3[m][n][i] - mean) * inv + bc[n];
    }
}

extern "C" void kernel_launch(void* const* d_in, const int* in_sizes, int n_in,
                              void* d_out, int out_size, void* d_ws, size_t ws_size,
                              hipStream_t stream) {
  const float* hV = (const float*)d_in[0];
  const float* hE = (const float*)d_in[1];
  const int* Eidx = (const int*)d_in[2];
  const float* maskV = (const float*)d_in[3];
  const float* mattend = (const float*)d_in[4];
  const float* W1w = (const float*)d_in[5];   const float* W1b = (const float*)d_in[6];
  const float* W2w = (const float*)d_in[7];   const float* W2b = (const float*)d_in[8];
  const float* W3w = (const float*)d_in[9];   const float* W3b = (const float*)d_in[10];
  const float* W11w = (const float*)d_in[11]; const float* W11b = (const float*)d_in[12];
  const float* W12w = (const float*)d_in[13]; const float* W12b = (const float*)d_in[14];
  const float* W13w = (const float*)d_in[15]; const float* W13b = (const float*)d_in[16];
  const float* n1g = (const float*)d_in[17];  const float* n1b = (const float*)d_in[18];
  const float* n2g = (const float*)d_in[19];  const float* n2b = (const float*)d_in[20];
  const float* n3g = (const float*)d_in[21];  const float* n3b = (const float*)d_in[22];
  const float* dinw = (const float*)d_in[23]; const float* dinb = (const float*)d_in[24];
  const float* doutw = (const float*)d_in[25]; const float* doutb = (const float*)d_in[26];

  // ws layout (bytes), peak == proven 13,172,736:
  //   [0, 589824)          wc  (bf16 weights)
  //   [589824, 8978432)    Region1: Y1 (k1 phase) -> hV2c (1st half) + Y2c (2nd half)
  //   [8978432, 13172736)  Region2: hV1b (k1/k2) -> Y2n (k3 phase)
  unsigned short* wc   = (unsigned short*)d_ws;
  unsigned short* R1   = wc + 294912;
  unsigned short* R2   = R1 + 4194304;
  unsigned short* Y1   = R1;            // [BN][256] bf16
  unsigned short* hV1b = R2;            // [BN][128] bf16
  unsigned short* hV2c = R1;            // [BN][128] bf16 (Y1 dead after k1)
  unsigned short* Y2c  = R1 + 2097152;  // [BN][128] bf16
  unsigned short* Y2n  = R2;            // [BN][128] bf16 (hV1b dead after k2)

  float* outV = (float*)d_out;
  float* outE = outV + (size_t)B_ * N_ * H_;

  prep<<<1152, 256, 0, stream>>>(W1w, W2w, W3w, W11w, W12w, W13w, dinw, doutw, wc);
  preY<true, false><<<256, 256, 0, stream>>>(hV, wc, Y1, Y1);
  k1<<<8192, 256, 0, stream>>>(hV, hE, Eidx, mattend, wc, Y1,
                               W1b, W2b, W3b, n1g, n1b, hV1b, outE);
  k2<<<1024, 256, 0, stream>>>(hV1b, wc, dinb, doutb, n2g, n2b, maskV, outV, hV2c);
  preY<false, true><<<256, 256, 0, stream>>>(hV2c, wc + 81920, Y2c, Y2n);
  k3<<<8192, 256, 0, stream>>>(Eidx, wc, Y2c, Y2n,
                               W11b, W12b, W13b, n3g, n3b, outE);
}